// Round 7
// baseline (184.507 us; speedup 1.0000x reference)
//
#include <hip/hip_runtime.h>

#define C_CLS 50
#define B_TR 8
#define T_FULL 600
#define T_USE 500
#define N_NEU 30000
#define NGRP 118          // ceil(30000/256) groups of 256 neurons
#define NGRP_PAD 120      // padded (build only) so bitset rows end in zeros
#define NWORDS 472        // NGRP*4 u64 ballot words per row
#define WPC 480           // u64 stride per class bitset row (16B aligned)
#define NBINS 16
#define EPS 1e-7
#define LDS_STRIDE 501    // floats; odd -> conflict-free lane-per-class reads

__device__ __constant__ int d_bins[NBINS] = {1,1,2,3,4,6,9,13,18,26,38,55,78,113,162,234};

// ws layout (bytes):
//   flags        @ 0      int[8]
//   ncls         @ 256    int[8]
//   cls_of_trial @ 512    int[8*64]
//   bits         @ 8192   u64[50*480] (192,000 B; rows 3840 B)
//   selected     @ 204800 float[50*500] (100,000 B)

// ---------------------------------------------------------------------------
// init_tc: one wave. Zero detect flags; invert sample_trials into per-trial
// class lists via ballot (deterministic: position = popcount of lower lanes).
// ---------------------------------------------------------------------------
__global__ void init_tc_kernel(const int* __restrict__ trials, int* flags,
                               int* ncls, int* cls_of_trial) {
    int lane = threadIdx.x; // 64 threads
    if (lane < 8) flags[lane] = 0;
    int b = (lane < C_CLS) ? trials[lane] : -1;
    for (int bb = 0; bb < B_TR; ++bb) {
        unsigned long long m = __ballot(b == bb);
        if (b == bb) {
            int pos = __popcll(m & ((1ull << lane) - 1ull));
            cls_of_trial[bb * 64 + pos] = lane;
        }
        if (lane == 0) ncls[bb] = __popcll(m);
    }
}

// ---------------------------------------------------------------------------
// detect: classify the bool sel_mask buffer encoding.
// modes: 0=int32, 1=uint8, 2=float32, 3=int64, 4=float64
// ---------------------------------------------------------------------------
__global__ void detect_mode_kernel(const unsigned int* __restrict__ w, int* flags) {
    const int nwords = C_CLS * N_NEU / 4; // smallest possible buffer in words
    int stride = gridDim.x * blockDim.x;
    int fF = 0, fB = 0, fO = 0, fD = 0;
    for (int i = blockIdx.x * blockDim.x + threadIdx.x; i < nwords; i += stride) {
        unsigned int v = w[i];
        if (v == 0u) continue;
        if (v == 0x3F800000u) fF = 1;
        else if (v == 0x3FF00000u && (i & 1)) fD = 1;
        else {
            unsigned int b0 = v & 0xFFu, b1 = (v >> 8) & 0xFFu,
                         b2 = (v >> 16) & 0xFFu, b3 = (v >> 24) & 0xFFu;
            bool byteOK = (b0 <= 1u) && (b1 <= 1u) && (b2 <= 1u) && (b3 <= 1u);
            if (byteOK && v != 1u) fB = 1;
        }
        if (i & 1) fO = 1;
    }
    if (fF) atomicOr(&flags[0], 1);
    if (fB) atomicOr(&flags[1], 1);
    if (fO) atomicOr(&flags[2], 1);
    if (fD) atomicOr(&flags[3], 1);
}

__device__ __forceinline__ int mode_from_flags(const int* flags) {
    if (flags[0]) return 2;
    if (flags[3]) return 4;
    if (flags[1]) return 1;
    if (flags[2]) return 0;
    return 3;
}

__device__ __forceinline__ bool load_sel(const void* mask, int mode, long long e) {
    switch (mode) {
        case 0:  return ((const int*)mask)[e] != 0;
        case 1:  return ((const unsigned char*)mask)[e] != 0;
        case 2:  return ((const float*)mask)[e] != 0.0f;
        case 3:  return ((const long long*)mask)[e] != 0LL;
        default: return ((const double*)mask)[e] != 0.0;
    }
}

// ---------------------------------------------------------------------------
// build_bits: class bitsets in INTERLEAVED order matching the float4 ballot:
// word (g,k) bit l = mask[c][g*256 + l*4 + k] at bits[c*WPC + g*4 + k].
// Groups 118,119 produce all-zero words (row padding) and OOB bits are 0,
// auto-masking the stream kernel's clamped duplicate loads.
// ---------------------------------------------------------------------------
__global__ void build_bits_kernel(const void* mask, const int* flags,
                                  unsigned long long* bits) {
    int c = blockIdx.x;
    int lane = threadIdx.x; // 64 = 1 wave
    int mode = mode_from_flags(flags);
    for (int g = blockIdx.y; g < NGRP_PAD; g += gridDim.y) {
        int base = g * 256 + lane * 4;
        long long e = (long long)c * N_NEU + base;
        bool s0 = (base + 0 < N_NEU) && load_sel(mask, mode, e + 0);
        bool s1 = (base + 1 < N_NEU) && load_sel(mask, mode, e + 1);
        bool s2 = (base + 2 < N_NEU) && load_sel(mask, mode, e + 2);
        bool s3 = (base + 3 < N_NEU) && load_sel(mask, mode, e + 3);
        unsigned long long w0 = __ballot(s0);
        unsigned long long w1 = __ballot(s1);
        unsigned long long w2 = __ballot(s2);
        unsigned long long w3 = __ballot(s3);
        if (lane == 0) {
            long long o = (long long)c * WPC + g * 4;
            bits[o + 0] = w0; bits[o + 1] = w1;
            bits[o + 2] = w2; bits[o + 3] = w3;
        }
    }
}

// ---------------------------------------------------------------------------
// stream: one block per (trial,t) row.
// Phase 1: ballot the whole 30000-float row into LDS (472 u64 words).
//          Spike loads are float4, fully coalesced; ballot results are
//          wave-uniform SGPRs, lane 0 writes them.
// Phase 2: per class of this trial (~6), all 256 threads AND+popcount the
//          LDS words against the class bitset read COALESCEDLY (thread i ->
//          word i; consecutive 8B/lane from the L2-resident 188KB table),
//          then wave shuffle-reduce. No address divergence anywhere.
// Exactly one block writes each selected[c][t] -> deterministic, no atomics.
// ---------------------------------------------------------------------------
__global__ void __launch_bounds__(256)
stream_kernel(const float* __restrict__ spikes,
              const int* __restrict__ ncls,
              const int* __restrict__ cls_of_trial,
              const unsigned long long* __restrict__ bits,
              float* __restrict__ selected) {
    __shared__ unsigned long long sbits[NWORDS]; // 3776 B
    __shared__ int wsum[52][4];                  // 832 B
    int bt = blockIdx.x;
    int b = bt / T_USE;
    int t = bt - b * T_USE;
    int nc = ncls[b];
    if (nc == 0) return;
    int lane = threadIdx.x & 63;
    int wid = threadIdx.x >> 6;
    const float4* __restrict__ row4 =
        (const float4*)(spikes + ((long long)b * T_FULL + t) * N_NEU);

    // ---- phase 1: row -> ballot words in LDS
    int g0 = wid * 30;
    int g1 = g0 + 30; if (g1 > NGRP) g1 = NGRP; // waves: 30,30,30,28 groups
    int g = g0;
    for (; g + 4 <= g1; g += 4) {
        float4 v[4];
#pragma unroll
        for (int u = 0; u < 4; ++u) {
            int ia = (g + u) * 64 + lane;
            if (ia > N_NEU / 4 - 1) ia = N_NEU / 4 - 1; // clamped dups: masked by zero bits
            v[u] = row4[ia];
        }
#pragma unroll
        for (int u = 0; u < 4; ++u) {
            unsigned long long b0 = __ballot(v[u].x != 0.0f);
            unsigned long long b1 = __ballot(v[u].y != 0.0f);
            unsigned long long b2 = __ballot(v[u].z != 0.0f);
            unsigned long long b3 = __ballot(v[u].w != 0.0f);
            if (lane == 0) {
                int o = (g + u) * 4;
                sbits[o + 0] = b0; sbits[o + 1] = b1;
                sbits[o + 2] = b2; sbits[o + 3] = b3;
            }
        }
    }
    for (; g < g1; ++g) {
        int ia = g * 64 + lane;
        if (ia > N_NEU / 4 - 1) ia = N_NEU / 4 - 1;
        float4 v = row4[ia];
        unsigned long long b0 = __ballot(v.x != 0.0f);
        unsigned long long b1 = __ballot(v.y != 0.0f);
        unsigned long long b2 = __ballot(v.z != 0.0f);
        unsigned long long b3 = __ballot(v.w != 0.0f);
        if (lane == 0) {
            int o = g * 4;
            sbits[o + 0] = b0; sbits[o + 1] = b1;
            sbits[o + 2] = b2; sbits[o + 3] = b3;
        }
    }
    __syncthreads();

    // ---- phase 2: per-class coalesced AND+popcount
    int i0 = threadIdx.x;
    int i1 = threadIdx.x + 256;           // < 472 for threadIdx.x < 216
    unsigned long long s0 = sbits[i0];
    unsigned long long s1 = (i1 < NWORDS) ? sbits[i1] : 0ull;
    for (int kc = 0; kc < nc; ++kc) {
        int c = cls_of_trial[b * 64 + kc];
        const unsigned long long* __restrict__ bp = bits + (long long)c * WPC;
        int p = __popcll(s0 & bp[i0]);
        if (i1 < NWORDS) p += __popcll(s1 & bp[i1]);
        for (int off = 32; off > 0; off >>= 1) p += __shfl_down(p, off);
        if (lane == 0) wsum[kc][wid] = p;
    }
    __syncthreads();
    if (threadIdx.x < nc) {
        int c = cls_of_trial[b * 64 + threadIdx.x];
        int s = wsum[threadIdx.x][0] + wsum[threadIdx.x][1]
              + wsum[threadIdx.x][2] + wsum[threadIdx.x][3];
        selected[c * T_USE + t] = (float)s;
    }
}

// ---------------------------------------------------------------------------
// fano_loss: one block, 16 waves (wave = bin). Stage `selected` into LDS
// with coalesced float4 loads (stride-501 padding -> conflict-free
// lane-per-class reads); lane c accumulates bin sums in double (exact);
// wave 0 does the MSE.
// ---------------------------------------------------------------------------
__global__ void __launch_bounds__(1024)
fano_loss_kernel(const float* __restrict__ selected,
                 const float* __restrict__ exp_fanos,
                 float* __restrict__ out) {
    __shared__ float lds[C_CLS * LDS_STRIDE]; // 100,200 B
    __shared__ float sf[NBINS];
    const float4* __restrict__ sel4 = (const float4*)selected;
    for (int i = threadIdx.x; i < C_CLS * T_USE / 4; i += 1024) {
        float4 v = sel4[i];
        int r = i / (T_USE / 4);
        int p = (i - r * (T_USE / 4)) * 4;
        float* dst = &lds[r * LDS_STRIDE + p];
        dst[0] = v.x; dst[1] = v.y; dst[2] = v.z; dst[3] = v.w;
    }
    __syncthreads();
    int wid = threadIdx.x >> 6;
    int lane = threadIdx.x & 63;
    int b = d_bins[wid];
    int nb = T_USE / b;
    float fano = 0.f;
    if (lane < C_CLS) {
        const float* row = &lds[lane * LDS_STRIDE];
        double s1 = 0.0, s2 = 0.0;
        for (int i = 0; i < nb; ++i) {
            float cs = 0.f;
            int base = i * b;
            for (int j = 0; j < b; ++j) cs += row[base + j];
            s1 += cs;
            s2 += (double)cs * (double)cs;
        }
        double mean = s1 / nb;
        double var = s2 / nb - mean * mean;
        if (var < 0.0) var = 0.0;
        double m = mean > EPS ? mean : EPS;
        fano = (float)(var / m);
    }
    for (int off = 32; off > 0; off >>= 1) fano += __shfl_down(fano, off);
    if (lane == 0) sf[wid] = fano / (float)C_CLS;
    __syncthreads();
    if (wid == 0) {
        float sq = 0.f;
        if (lane < NBINS) {
            float d = exp_fanos[lane] - sf[lane];
            sq = d * d;
        }
        for (int off = 32; off > 0; off >>= 1) sq += __shfl_down(sq, off);
        if (lane == 0) out[0] = 10.0f * sq / (float)NBINS;
    }
}

extern "C" void kernel_launch(void* const* d_in, const int* in_sizes, int n_in,
                              void* d_out, int out_size, void* d_ws, size_t ws_size,
                              hipStream_t stream) {
    const float* spikes    = (const float*)d_in[0];
    const float* exp_fanos = (const float*)d_in[1];
    const int*   trials    = (const int*)d_in[2];
    const void*  mask      = d_in[3];
    float* out = (float*)d_out;

    char* ws = (char*)d_ws;
    int*   flags   = (int*)(ws + 0);
    int*   ncls    = (int*)(ws + 256);
    int*   clsofb  = (int*)(ws + 512);
    unsigned long long* bits = (unsigned long long*)(ws + 8192);
    float* selected = (float*)(ws + 204800);

    init_tc_kernel<<<1, 64, 0, stream>>>(trials, flags, ncls, clsofb);
    detect_mode_kernel<<<256, 256, 0, stream>>>((const unsigned int*)mask, flags);
    build_bits_kernel<<<dim3(C_CLS, 8), 64, 0, stream>>>(mask, flags, bits);
    stream_kernel<<<B_TR * T_USE, 256, 0, stream>>>(spikes, ncls, clsofb, bits, selected);
    fano_loss_kernel<<<1, 1024, 0, stream>>>(selected, exp_fanos, out);
}

// Round 8
// 181.316 us; speedup vs baseline: 1.0176x; 1.0176x over previous
//
#include <hip/hip_runtime.h>

#define C_CLS 50
#define B_TR 8
#define T_FULL 600
#define T_USE 500
#define N_NEU 30000
#define NGRP 118          // ceil(30000/256) groups of 256 neurons
#define NGRP_PAD 120      // padded so bitset rows end in zero words
#define WPC 480           // u64 words per class bitset row = NGRP_PAD*4
#define NQ 30             // quads per row (NGRP_PAD/4)
#define TPB 4             // t-rows per stream block
#define NBINS 16
#define EPS 1e-7
#define LDS_STRIDE 501    // floats; odd -> conflict-free lane-per-class reads

__device__ __constant__ int d_bins[NBINS] = {1,1,2,3,4,6,9,13,18,26,38,55,78,113,162,234};

// ws layout (bytes):
//   verdict      @ 0      int[256]  (per-detect-block packed flags, no init needed)
//   ncls         @ 1024   int[8]
//   cls_of_trial @ 1280   int[8*64]
//   bits         @ 8192   u64[50*480] (192,000 B)
//   selected     @ 204800 float[50*500] (100,000 B)

// verdict bits: 1=f32 pattern, 2=packed-bytes, 4=odd-word-nonzero, 8=f64 pattern
__device__ __forceinline__ int mode_from_verdict(int v) {
    if (v & 1) return 2;   // float32
    if (v & 8) return 4;   // float64
    if (v & 2) return 1;   // uint8
    if (v & 4) return 0;   // int32
    return 3;              // int64
}

__device__ __forceinline__ bool load_sel(const void* mask, int mode, long long e) {
    switch (mode) {
        case 0:  return ((const int*)mask)[e] != 0;
        case 1:  return ((const unsigned char*)mask)[e] != 0;
        case 2:  return ((const float*)mask)[e] != 0.0f;
        case 3:  return ((const long long*)mask)[e] != 0LL;
        default: return ((const double*)mask)[e] != 0.0;
    }
}

// ---------------------------------------------------------------------------
// detect: 256 blocks, each scans its word partition and stores a packed
// verdict (plain store -> no pre-zero, no atomics). Block 0 wave 0 also
// inverts sample_trials into per-trial class lists (ballot-deterministic).
// ---------------------------------------------------------------------------
__global__ void __launch_bounds__(256)
detect_kernel(const unsigned int* __restrict__ w, const int* __restrict__ trials,
              int* verdict, int* ncls, int* cls_of_trial) {
    __shared__ int sfl;
    if (threadIdx.x == 0) sfl = 0;
    __syncthreads();
    const int nwords = C_CLS * N_NEU / 4; // 375000 (smallest possible buffer)
    int per = (nwords + gridDim.x - 1) / gridDim.x;
    int beg = blockIdx.x * per;
    int end = beg + per; if (end > nwords) end = nwords;
    int f = 0;
    for (int i = beg + threadIdx.x; i < end; i += blockDim.x) {
        unsigned int v = w[i];
        if (v == 0u) continue;
        if (v == 0x3F800000u) f |= 1;
        else if (v == 0x3FF00000u && (i & 1)) f |= 8;
        else {
            unsigned int b0 = v & 0xFFu, b1 = (v >> 8) & 0xFFu,
                         b2 = (v >> 16) & 0xFFu, b3 = (v >> 24) & 0xFFu;
            bool byteOK = (b0 <= 1u) && (b1 <= 1u) && (b2 <= 1u) && (b3 <= 1u);
            if (byteOK && v != 1u) f |= 2;
        }
        if (i & 1) f |= 4;
    }
    if (f) atomicOr(&sfl, f);
    __syncthreads();
    if (threadIdx.x == 0) verdict[blockIdx.x] = sfl;

    if (blockIdx.x == 0 && threadIdx.x < 64) {
        int lane = threadIdx.x;
        int b = (lane < C_CLS) ? trials[lane] : -1;
        for (int bb = 0; bb < B_TR; ++bb) {
            unsigned long long m = __ballot(b == bb);
            if (b == bb) {
                int pos = __popcll(m & ((1ull << lane) - 1ull));
                cls_of_trial[bb * 64 + pos] = lane;
            }
            if (lane == 0) ncls[bb] = __popcll(m);
        }
    }
}

// ---------------------------------------------------------------------------
// build_bits: class bitsets in INTERLEAVED order matching the float4 ballot:
// word (g,k) bit l = mask[c][g*256 + l*4 + k] at bits[c*WPC + g*4 + k].
// Groups 118,119 give all-zero words, auto-masking clamped stream loads.
// Mode is OR-reduced from the 256 verdict words (L2-resident, ~20 instr).
// ---------------------------------------------------------------------------
__global__ void build_bits_kernel(const void* mask, const int* __restrict__ verdict,
                                  unsigned long long* bits) {
    int c = blockIdx.x;
    int lane = threadIdx.x; // 64 = 1 wave
    int v = verdict[lane] | verdict[lane + 64] | verdict[lane + 128] | verdict[lane + 192];
    for (int off = 32; off > 0; off >>= 1) v |= __shfl_xor(v, off);
    int mode = mode_from_verdict(v);
    for (int g = blockIdx.y; g < NGRP_PAD; g += gridDim.y) {
        int base = g * 256 + lane * 4;
        long long e = (long long)c * N_NEU + base;
        bool s0 = (base + 0 < N_NEU) && load_sel(mask, mode, e + 0);
        bool s1 = (base + 1 < N_NEU) && load_sel(mask, mode, e + 1);
        bool s2 = (base + 2 < N_NEU) && load_sel(mask, mode, e + 2);
        bool s3 = (base + 3 < N_NEU) && load_sel(mask, mode, e + 3);
        unsigned long long w0 = __ballot(s0);
        unsigned long long w1 = __ballot(s1);
        unsigned long long w2 = __ballot(s2);
        unsigned long long w3 = __ballot(s3);
        if (lane == 0) {
            long long o = (long long)c * WPC + g * 4;
            bits[o + 0] = w0; bits[o + 1] = w1;
            bits[o + 2] = w2; bits[o + 3] = w3;
        }
    }
}

// ---------------------------------------------------------------------------
// stream: one block per (trial, 4 consecutive t). Wave w ballots row t0+w
// into sbits[w] (float4 coalesced loads, 30 quads). Phase 2: each thread
// holds LDS words i0,i0+256 of all 4 rows; per class (~6), the bitset words
// are read coalescedly ONCE and popcounted against 4 rows (packed 2x16-bit
// shuffle reduce). One writer per (c,t) -> deterministic, no atomics.
// ---------------------------------------------------------------------------
__global__ void __launch_bounds__(256)
stream_kernel(const float* __restrict__ spikes,
              const int* __restrict__ ncls,
              const int* __restrict__ cls_of_trial,
              const unsigned long long* __restrict__ bits,
              float* __restrict__ selected) {
    __shared__ unsigned long long sbits[TPB][WPC]; // 15,360 B
    __shared__ int wsum2[C_CLS][4][2];             // 1,600 B
    int bt = blockIdx.x;                 // 0..999
    int b = bt / (T_USE / TPB);          // /125
    int tq = bt - b * (T_USE / TPB);
    int t0 = tq * TPB;
    int nc = ncls[b];
    if (nc == 0) return;
    int lane = threadIdx.x & 63;
    int wid = threadIdx.x >> 6;
    const float4* __restrict__ row4 =
        (const float4*)(spikes + ((long long)(b * T_FULL + t0 + wid)) * N_NEU);

    // ---- phase 1: wave wid -> ballot words of its row
    for (int q = 0; q < NQ; ++q) {
        float4 v[4];
#pragma unroll
        for (int u = 0; u < 4; ++u) {
            int ia = (q * 4 + u) * 64 + lane;
            if (ia > N_NEU / 4 - 1) ia = N_NEU / 4 - 1; // dups masked by zero bits
            v[u] = row4[ia];
        }
#pragma unroll
        for (int u = 0; u < 4; ++u) {
            unsigned long long b0 = __ballot(v[u].x != 0.0f);
            unsigned long long b1 = __ballot(v[u].y != 0.0f);
            unsigned long long b2 = __ballot(v[u].z != 0.0f);
            unsigned long long b3 = __ballot(v[u].w != 0.0f);
            if (lane == 0) {
                int o = (q * 4 + u) * 4;
                sbits[wid][o + 0] = b0; sbits[wid][o + 1] = b1;
                sbits[wid][o + 2] = b2; sbits[wid][o + 3] = b3;
            }
        }
    }
    __syncthreads();

    // ---- phase 2: coalesced bitset read, 4-row popcount
    int i0 = threadIdx.x;
    int i1 = threadIdx.x + 256;
    bool has1 = (i1 < WPC);
    unsigned long long s00 = sbits[0][i0], s10 = sbits[1][i0],
                       s20 = sbits[2][i0], s30 = sbits[3][i0];
    unsigned long long s01 = 0, s11 = 0, s21 = 0, s31 = 0;
    if (has1) { s01 = sbits[0][i1]; s11 = sbits[1][i1];
                s21 = sbits[2][i1]; s31 = sbits[3][i1]; }
    for (int kc = 0; kc < nc; ++kc) {
        int c = cls_of_trial[b * 64 + kc];
        const unsigned long long* __restrict__ bp = bits + (long long)c * WPC;
        unsigned long long w0 = bp[i0];
        unsigned long long w1 = has1 ? bp[i1] : 0ull;
        int p0 = __popcll(s00 & w0) + __popcll(s01 & w1);
        int p1 = __popcll(s10 & w0) + __popcll(s11 & w1);
        int p2 = __popcll(s20 & w0) + __popcll(s21 & w1);
        int p3 = __popcll(s30 & w0) + __popcll(s31 & w1);
        int pa = p0 | (p1 << 16);   // per-lane <=128 each, wave sum <=8192: no carry
        int pb = p2 | (p3 << 16);
        for (int off = 32; off > 0; off >>= 1) {
            pa += __shfl_down(pa, off);
            pb += __shfl_down(pb, off);
        }
        if (lane == 0) { wsum2[kc][wid][0] = pa; wsum2[kc][wid][1] = pb; }
    }
    __syncthreads();
    if (threadIdx.x < nc * 4) {
        int kc = threadIdx.x >> 2, r = threadIdx.x & 3;
        int c = cls_of_trial[b * 64 + kc];
        int s = 0;
#pragma unroll
        for (int w = 0; w < 4; ++w) {
            int v = wsum2[kc][w][r >> 1];
            s += (r & 1) ? (v >> 16) : (v & 0xFFFF);
        }
        selected[c * T_USE + t0 + r] = (float)s;
    }
}

// ---------------------------------------------------------------------------
// fano_loss: one block, 16 waves (wave = bin). Stage `selected` into LDS
// (coalesced float4, stride-501 -> conflict-free lane-per-class reads);
// lane c accumulates bin sums in double (exact); wave 0 does the MSE.
// ---------------------------------------------------------------------------
__global__ void __launch_bounds__(1024)
fano_loss_kernel(const float* __restrict__ selected,
                 const float* __restrict__ exp_fanos,
                 float* __restrict__ out) {
    __shared__ float lds[C_CLS * LDS_STRIDE]; // 100,200 B
    __shared__ float sf[NBINS];
    const float4* __restrict__ sel4 = (const float4*)selected;
    for (int i = threadIdx.x; i < C_CLS * T_USE / 4; i += 1024) {
        float4 v = sel4[i];
        int r = i / (T_USE / 4);
        int p = (i - r * (T_USE / 4)) * 4;
        float* dst = &lds[r * LDS_STRIDE + p];
        dst[0] = v.x; dst[1] = v.y; dst[2] = v.z; dst[3] = v.w;
    }
    __syncthreads();
    int wid = threadIdx.x >> 6;
    int lane = threadIdx.x & 63;
    int b = d_bins[wid];
    int nb = T_USE / b;
    float fano = 0.f;
    if (lane < C_CLS) {
        const float* row = &lds[lane * LDS_STRIDE];
        double s1 = 0.0, s2 = 0.0;
        for (int i = 0; i < nb; ++i) {
            float cs = 0.f;
            int base = i * b;
            for (int j = 0; j < b; ++j) cs += row[base + j];
            s1 += cs;
            s2 += (double)cs * (double)cs;
        }
        double mean = s1 / nb;
        double var = s2 / nb - mean * mean;
        if (var < 0.0) var = 0.0;
        double m = mean > EPS ? mean : EPS;
        fano = (float)(var / m);
    }
    for (int off = 32; off > 0; off >>= 1) fano += __shfl_down(fano, off);
    if (lane == 0) sf[wid] = fano / (float)C_CLS;
    __syncthreads();
    if (wid == 0) {
        float sq = 0.f;
        if (lane < NBINS) {
            float d = exp_fanos[lane] - sf[lane];
            sq = d * d;
        }
        for (int off = 32; off > 0; off >>= 1) sq += __shfl_down(sq, off);
        if (lane == 0) out[0] = 10.0f * sq / (float)NBINS;
    }
}

extern "C" void kernel_launch(void* const* d_in, const int* in_sizes, int n_in,
                              void* d_out, int out_size, void* d_ws, size_t ws_size,
                              hipStream_t stream) {
    const float* spikes    = (const float*)d_in[0];
    const float* exp_fanos = (const float*)d_in[1];
    const int*   trials    = (const int*)d_in[2];
    const void*  mask      = d_in[3];
    float* out = (float*)d_out;

    char* ws = (char*)d_ws;
    int*   verdict = (int*)(ws + 0);
    int*   ncls    = (int*)(ws + 1024);
    int*   clsofb  = (int*)(ws + 1280);
    unsigned long long* bits = (unsigned long long*)(ws + 8192);
    float* selected = (float*)(ws + 204800);

    detect_kernel<<<256, 256, 0, stream>>>((const unsigned int*)mask, trials,
                                           verdict, ncls, clsofb);
    build_bits_kernel<<<dim3(C_CLS, 8), 64, 0, stream>>>(mask, verdict, bits);
    stream_kernel<<<B_TR * (T_USE / TPB), 256, 0, stream>>>(spikes, ncls, clsofb,
                                                            bits, selected);
    fano_loss_kernel<<<1, 1024, 0, stream>>>(selected, exp_fanos, out);
}